// Round 1
// baseline (34.429 us; speedup 1.0000x reference)
//
#include <hip/hip_runtime.h>

// PyBlaz 8x8 block DCT + int8 quantization, one thread per 8x8 block.
// Input: x (4096 x 4096 fp32). Outputs (concatenated in d_out as float32):
//   [0, 262144)              biggest (512 x 512)
//   [262144, 262144+16777216) indices as float (512 x 512 x 64)

#define IMG_W 4096
#define NB    512          // blocks per dim
#define NBLK  (NB * NB)    // 262144 total 8x8 blocks

__global__ __launch_bounds__(256) void dct_quant_kernel(
    const float* __restrict__ x,
    float* __restrict__ out_big,
    float* __restrict__ out_idx)
{
    const int bid = blockIdx.x * blockDim.x + threadIdx.x;  // 0..NBLK-1
    const int bi = bid >> 9;        // block row
    const int bj = bid & (NB - 1);  // block col

    // Orthonormal DCT-II matrix D[e][f] = scale(f) * cos(pi*(2e+1)*f/16)
    // scale(0)=sqrt(1/8), scale(f>0)=sqrt(2/8)=0.5. Baked as literals so the
    // fully-unrolled loops constant-fold (zero VGPR cost for D).
    const float s0 = 0.35355339059327373f;   // sqrt(1/8)
    const float d1 = 0.49039264020161522f;   // 0.5*cos(1*pi/16)
    const float d2 = 0.46193976625564337f;   // 0.5*cos(2*pi/16)
    const float d3 = 0.41573480615127262f;   // 0.5*cos(3*pi/16)
    const float d4 = 0.35355339059327379f;   // 0.5*cos(4*pi/16)
    const float d5 = 0.27778511650980114f;   // 0.5*cos(5*pi/16)
    const float d6 = 0.19134171618254492f;   // 0.5*cos(6*pi/16)
    const float d7 = 0.09754516100806413f;   // 0.5*cos(7*pi/16)

    const float D[8][8] = {
        { s0,  d1,  d2,  d3,  d4,  d5,  d6,  d7},
        { s0,  d3,  d6, -d7, -d4, -d1, -d2, -d5},
        { s0,  d5, -d6, -d1, -d4,  d7,  d2,  d3},
        { s0,  d7, -d2, -d5,  d4,  d3, -d6, -d1},
        { s0, -d7, -d2,  d5,  d4, -d3, -d6,  d1},
        { s0, -d5, -d6,  d1, -d4, -d7,  d2, -d3},
        { s0, -d3,  d6,  d7, -d4,  d1, -d2,  d5},
        { s0, -d1,  d2, -d3,  d4, -d5,  d6, -d7},
    };

    const float* p = x + (size_t)(bi * 8) * IMG_W + (size_t)bj * 8;

    float C[8][8];
#pragma unroll
    for (int g = 0; g < 8; ++g)
#pragma unroll
        for (int h = 0; h < 8; ++h) C[g][h] = 0.0f;

    // C = D^T * X * D, accumulated row-by-row:
    //   tmp[h] = sum_f X[e][f] * D[f][h]        (row transform)
    //   C[g][h] += D[e][g] * tmp[h]             (column transform)
#pragma unroll
    for (int e = 0; e < 8; ++e) {
        const float4 r0 = *reinterpret_cast<const float4*>(p + (size_t)e * IMG_W);
        const float4 r1 = *reinterpret_cast<const float4*>(p + (size_t)e * IMG_W + 4);
        const float row[8] = {r0.x, r0.y, r0.z, r0.w, r1.x, r1.y, r1.z, r1.w};

        float tmp[8];
#pragma unroll
        for (int h = 0; h < 8; ++h) {
            float acc = row[0] * D[0][h];
#pragma unroll
            for (int f = 1; f < 8; ++f) acc = fmaf(row[f], D[f][h], acc);
            tmp[h] = acc;
        }
#pragma unroll
        for (int g = 0; g < 8; ++g) {
#pragma unroll
            for (int h = 0; h < 8; ++h) C[g][h] = fmaf(D[e][g], tmp[h], C[g][h]);
        }
    }

    // Per-block abs-max
    float big = 0.0f;
#pragma unroll
    for (int g = 0; g < 8; ++g)
#pragma unroll
        for (int h = 0; h < 8; ++h) big = fmaxf(big, fabsf(C[g][h]));

    out_big[bid] = big;

    const float safe = (big == 0.0f) ? 1.0f : big;
    const float inv = 127.0f / safe;

    float* o = out_idx + (size_t)bid * 64;
#pragma unroll
    for (int g = 0; g < 8; ++g) {
        float4 q0, q1;
        q0.x = rintf(C[g][0] * inv);
        q0.y = rintf(C[g][1] * inv);
        q0.z = rintf(C[g][2] * inv);
        q0.w = rintf(C[g][3] * inv);
        q1.x = rintf(C[g][4] * inv);
        q1.y = rintf(C[g][5] * inv);
        q1.z = rintf(C[g][6] * inv);
        q1.w = rintf(C[g][7] * inv);
        *reinterpret_cast<float4*>(o + g * 8)     = q0;
        *reinterpret_cast<float4*>(o + g * 8 + 4) = q1;
    }
}

extern "C" void kernel_launch(void* const* d_in, const int* in_sizes, int n_in,
                              void* d_out, int out_size, void* d_ws, size_t ws_size,
                              hipStream_t stream) {
    const float* x = (const float*)d_in[0];
    float* out = (float*)d_out;
    float* out_big = out;                 // 262144 floats
    float* out_idx = out + NBLK;          // 16777216 floats

    dct_quant_kernel<<<NBLK / 256, 256, 0, stream>>>(x, out_big, out_idx);
}

// Round 2
// 26.441 us; speedup vs baseline: 1.3021x; 1.3021x over previous
//
#include <hip/hip_runtime.h>

// PyBlaz 8x8 block DCT + int8 quantization, one thread per 8x8 block.
// R1: LDS-staged coalesced output writes (R0 had 2.4x write amplification
// from 16-B stores at 256-B lane stride).
//
// Input: x (4096 x 4096 fp32). Outputs (concatenated in d_out as float32):
//   [0, 262144)               biggest (512 x 512)
//   [262144, 262144+16777216)  indices as float (512 x 512 x 64)

#define IMG_W 4096
#define NB    512          // blocks per dim
#define NBLK  (NB * NB)    // 262144 total 8x8 blocks

__global__ __launch_bounds__(256) void dct_quant_kernel(
    const float* __restrict__ x,
    float* __restrict__ out_big,
    float* __restrict__ out_idx)
{
    // 256 threads x 64 floats = 64 KB staging buffer, addressed in float4
    // slots with an XOR swizzle so both phases are bank-uniform.
    __shared__ float4 lds4[256 * 16];

    const int t   = threadIdx.x;
    const int bid = blockIdx.x * 256 + t;   // 0..NBLK-1
    const int bi  = bid >> 9;               // block row
    const int bj  = bid & (NB - 1);         // block col

    // Orthonormal DCT-II matrix D[e][f] = scale(f) * cos(pi*(2e+1)*f/16),
    // baked as literals so the fully-unrolled loops constant-fold.
    const float s0 = 0.35355339059327373f;   // sqrt(1/8)
    const float d1 = 0.49039264020161522f;
    const float d2 = 0.46193976625564337f;
    const float d3 = 0.41573480615127262f;
    const float d4 = 0.35355339059327379f;
    const float d5 = 0.27778511650980114f;
    const float d6 = 0.19134171618254492f;
    const float d7 = 0.09754516100806413f;

    const float D[8][8] = {
        { s0,  d1,  d2,  d3,  d4,  d5,  d6,  d7},
        { s0,  d3,  d6, -d7, -d4, -d1, -d2, -d5},
        { s0,  d5, -d6, -d1, -d4,  d7,  d2,  d3},
        { s0,  d7, -d2, -d5,  d4,  d3, -d6, -d1},
        { s0, -d7, -d2,  d5,  d4, -d3, -d6,  d1},
        { s0, -d5, -d6,  d1, -d4, -d7,  d2, -d3},
        { s0, -d3,  d6,  d7, -d4,  d1, -d2,  d5},
        { s0, -d1,  d2, -d3,  d4, -d5,  d6, -d7},
    };

    const float* p = x + (size_t)(bi * 8) * IMG_W + (size_t)bj * 8;

    float C[8][8];
#pragma unroll
    for (int g = 0; g < 8; ++g)
#pragma unroll
        for (int h = 0; h < 8; ++h) C[g][h] = 0.0f;

    // C = D^T * X * D, accumulated row-by-row:
    //   tmp[h] = sum_f X[e][f] * D[f][h]   (row transform)
    //   C[g][h] += D[e][g] * tmp[h]        (column transform)
#pragma unroll
    for (int e = 0; e < 8; ++e) {
        const float4 r0 = *reinterpret_cast<const float4*>(p + (size_t)e * IMG_W);
        const float4 r1 = *reinterpret_cast<const float4*>(p + (size_t)e * IMG_W + 4);
        const float row[8] = {r0.x, r0.y, r0.z, r0.w, r1.x, r1.y, r1.z, r1.w};

        float tmp[8];
#pragma unroll
        for (int h = 0; h < 8; ++h) {
            float acc = row[0] * D[0][h];
#pragma unroll
            for (int f = 1; f < 8; ++f) acc = fmaf(row[f], D[f][h], acc);
            tmp[h] = acc;
        }
#pragma unroll
        for (int g = 0; g < 8; ++g) {
#pragma unroll
            for (int h = 0; h < 8; ++h) C[g][h] = fmaf(D[e][g], tmp[h], C[g][h]);
        }
    }

    // Per-block abs-max
    float big = 0.0f;
#pragma unroll
    for (int g = 0; g < 8; ++g)
#pragma unroll
        for (int h = 0; h < 8; ++h) big = fmaxf(big, fabsf(C[g][h]));

    out_big[bid] = big;   // dword store, lane-contiguous -> already coalesced

    const float safe = (big == 0.0f) ? 1.0f : big;
    const float inv  = 127.0f / safe;

    // Quantize and scatter into LDS (swizzled slots, bank-uniform).
#pragma unroll
    for (int g = 0; g < 8; ++g) {
        float4 q0, q1;
        q0.x = rintf(C[g][0] * inv);
        q0.y = rintf(C[g][1] * inv);
        q0.z = rintf(C[g][2] * inv);
        q0.w = rintf(C[g][3] * inv);
        q1.x = rintf(C[g][4] * inv);
        q1.y = rintf(C[g][5] * inv);
        q1.z = rintf(C[g][6] * inv);
        q1.w = rintf(C[g][7] * inv);
        const int sA = 2 * g;
        const int sB = 2 * g + 1;
        lds4[t * 16 + (sA ^ (t & 15))] = q0;
        lds4[t * 16 + (sB ^ (t & 15))] = q1;
    }

    __syncthreads();

    // Cooperative coalesced copy: 4096 float4s per workgroup, 16 per thread.
    // Per instruction a wave stores 64 consecutive float4s = 1 KB dense.
    float4* og = reinterpret_cast<float4*>(out_idx) + (size_t)blockIdx.x * 4096;
#pragma unroll
    for (int k = 0; k < 16; ++k) {
        const int F   = k * 256 + t;    // flat float4 index in this WG's region
        const int blk = F >> 4;         // owning thread
        const int s   = F & 15;         // slot within owner
        og[F] = lds4[blk * 16 + (s ^ (blk & 15))];
    }
}

extern "C" void kernel_launch(void* const* d_in, const int* in_sizes, int n_in,
                              void* d_out, int out_size, void* d_ws, size_t ws_size,
                              hipStream_t stream) {
    const float* x = (const float*)d_in[0];
    float* out = (float*)d_out;
    float* out_big = out;          // 262144 floats
    float* out_idx = out + NBLK;   // 16777216 floats

    dct_quant_kernel<<<NBLK / 256, 256, 0, stream>>>(x, out_big, out_idx);
}

// Round 3
// 25.539 us; speedup vs baseline: 1.3481x; 1.0353x over previous
//
#include <hip/hip_runtime.h>

// PyBlaz 8x8 block DCT + int8 quantization, one thread per 8x8 block.
// R2: stage int8-packed payload in LDS (17 KB) instead of floats (64 KB)
// to lift the occupancy cap (R1: 2 WG/CU, 18% occupancy); unpack to float
// during the coalesced copy-out.
//
// Input: x (4096 x 4096 fp32). Outputs (concatenated in d_out as float32):
//   [0, 262144)               biggest (512 x 512)
//   [262144, 262144+16777216)  indices as float (512 x 512 x 64)

#define IMG_W 4096
#define NB    512          // blocks per dim
#define NBLK  (NB * NB)    // 262144 total 8x8 blocks

__global__ __launch_bounds__(256) void dct_quant_kernel(
    const float* __restrict__ x,
    float* __restrict__ out_big,
    float* __restrict__ out_idx)
{
    // 256 threads x 16 packed u32 (64 int8) each; stride 17 (odd) makes the
    // per-thread column scatter a perfect bank permutation.
    __shared__ unsigned int lds[256 * 17];

    const int t   = threadIdx.x;
    const int bid = blockIdx.x * 256 + t;   // 0..NBLK-1
    const int bi  = bid >> 9;               // block row
    const int bj  = bid & (NB - 1);         // block col

    // Orthonormal DCT-II matrix D[e][f] = scale(f) * cos(pi*(2e+1)*f/16),
    // baked as literals so the fully-unrolled loops constant-fold.
    const float s0 = 0.35355339059327373f;   // sqrt(1/8)
    const float d1 = 0.49039264020161522f;
    const float d2 = 0.46193976625564337f;
    const float d3 = 0.41573480615127262f;
    const float d4 = 0.35355339059327379f;
    const float d5 = 0.27778511650980114f;
    const float d6 = 0.19134171618254492f;
    const float d7 = 0.09754516100806413f;

    const float D[8][8] = {
        { s0,  d1,  d2,  d3,  d4,  d5,  d6,  d7},
        { s0,  d3,  d6, -d7, -d4, -d1, -d2, -d5},
        { s0,  d5, -d6, -d1, -d4,  d7,  d2,  d3},
        { s0,  d7, -d2, -d5,  d4,  d3, -d6, -d1},
        { s0, -d7, -d2,  d5,  d4, -d3, -d6,  d1},
        { s0, -d5, -d6,  d1, -d4, -d7,  d2, -d3},
        { s0, -d3,  d6,  d7, -d4,  d1, -d2,  d5},
        { s0, -d1,  d2, -d3,  d4, -d5,  d6, -d7},
    };

    const float* p = x + (size_t)(bi * 8) * IMG_W + (size_t)bj * 8;

    float C[8][8];
#pragma unroll
    for (int g = 0; g < 8; ++g)
#pragma unroll
        for (int h = 0; h < 8; ++h) C[g][h] = 0.0f;

    // C = D^T * X * D, accumulated row-by-row:
    //   tmp[h] = sum_f X[e][f] * D[f][h]   (row transform)
    //   C[g][h] += D[e][g] * tmp[h]        (column transform)
#pragma unroll
    for (int e = 0; e < 8; ++e) {
        const float4 r0 = *reinterpret_cast<const float4*>(p + (size_t)e * IMG_W);
        const float4 r1 = *reinterpret_cast<const float4*>(p + (size_t)e * IMG_W + 4);
        const float row[8] = {r0.x, r0.y, r0.z, r0.w, r1.x, r1.y, r1.z, r1.w};

        float tmp[8];
#pragma unroll
        for (int h = 0; h < 8; ++h) {
            float acc = row[0] * D[0][h];
#pragma unroll
            for (int f = 1; f < 8; ++f) acc = fmaf(row[f], D[f][h], acc);
            tmp[h] = acc;
        }
#pragma unroll
        for (int g = 0; g < 8; ++g) {
#pragma unroll
            for (int h = 0; h < 8; ++h) C[g][h] = fmaf(D[e][g], tmp[h], C[g][h]);
        }
    }

    // Per-block abs-max
    float big = 0.0f;
#pragma unroll
    for (int g = 0; g < 8; ++g)
#pragma unroll
        for (int h = 0; h < 8; ++h) big = fmaxf(big, fabsf(C[g][h]));

    out_big[bid] = big;   // dword store, lane-contiguous -> already coalesced

    const float safe = (big == 0.0f) ? 1.0f : big;
    const float inv  = 127.0f / safe;

    // Quantize to int8, pack 4 per u32, stage in LDS.
#pragma unroll
    for (int g = 0; g < 8; ++g) {
        int q[8];
#pragma unroll
        for (int h = 0; h < 8; ++h) q[h] = (int)rintf(C[g][h] * inv);  // [-127,127]
        const unsigned int w0 = (q[0] & 0xff) | ((q[1] & 0xff) << 8) |
                                ((q[2] & 0xff) << 16) | ((unsigned)(q[3] & 0xff) << 24);
        const unsigned int w1 = (q[4] & 0xff) | ((q[5] & 0xff) << 8) |
                                ((q[6] & 0xff) << 16) | ((unsigned)(q[7] & 0xff) << 24);
        lds[t * 17 + 2 * g]     = w0;
        lds[t * 17 + 2 * g + 1] = w1;
    }

    __syncthreads();

    // Coalesced copy-out: 4096 float4s per WG; each float4 unpacks one u32.
    float4* og = reinterpret_cast<float4*>(out_idx) + (size_t)blockIdx.x * 4096;
#pragma unroll
    for (int k = 0; k < 16; ++k) {
        const int F = k * 256 + t;          // flat u32 index in this WG's region
        const unsigned int w = lds[(F >> 4) * 17 + (F & 15)];
        float4 q;
        q.x = (float)(int)(signed char)(w       & 0xff);
        q.y = (float)(int)(signed char)((w >> 8)  & 0xff);
        q.z = (float)(int)(signed char)((w >> 16) & 0xff);
        q.w = (float)(int)(signed char)(w >> 24);
        og[F] = q;
    }
}

extern "C" void kernel_launch(void* const* d_in, const int* in_sizes, int n_in,
                              void* d_out, int out_size, void* d_ws, size_t ws_size,
                              hipStream_t stream) {
    const float* x = (const float*)d_in[0];
    float* out = (float*)d_out;
    float* out_big = out;          // 262144 floats
    float* out_idx = out + NBLK;   // 16777216 floats

    dct_quant_kernel<<<NBLK / 256, 256, 0, stream>>>(x, out_big, out_idx);
}